// Round 11
// baseline (937.527 us; speedup 1.0000x reference)
//
#include <hip/hip_runtime.h>
#include <stdint.h>

#define N_ATOMS 8192
#define EMBED   32
#define DEPTHN  10

typedef short bf16x8 __attribute__((ext_vector_type(8)));
typedef float f32x4  __attribute__((ext_vector_type(4)));

__device__ __forceinline__ unsigned short f2bf(float f){
    unsigned u = __builtin_bit_cast(unsigned, f);
    u = u + 0x7FFFu + ((u >> 16) & 1u);
    return (unsigned short)(u >> 16);
}

// ---------------------------------------------------------------------------
// k_preA: 16-row group per block. Reads A rows, produces:
//  - mP: bitmask packed in MFMA-A-fragment order:
//      mP[(rt*256 + g)*16 + n] = bits of row rt*16+n, cols g*32..g*32+31
//  - deg/invdeg (folded in).
// All 512 KiB of A-row reads complete (LDS-staged) before any global write,
// so the A-tail aliasing fallback (chunked descending groups) is safe.
// ---------------------------------------------------------------------------
__global__ __launch_bounds__(256) void k_preA(const int* __restrict__ A,
                                              unsigned* __restrict__ mP,
                                              float* __restrict__ deg,
                                              float* __restrict__ invdeg,
                                              int g0)
{
    const int grp = g0 + blockIdx.x;            // 16-row group, 0..511
    const int t = threadIdx.x, w = t >> 6, l = t & 63;
    __shared__ unsigned lm[16][256];            // 16 KiB
    __shared__ int red[256];
    for (int rr = 0; rr < 16; ++rr){
        const int* row = A + (size_t)(grp*16 + rr) * N_ATOMS;
        for (int k = 0; k < 32; ++k){
            unsigned long long m = __ballot(row[k*256 + t] != 0);
            if (l == 0){
                lm[rr][k*8 + w*2]     = (unsigned)m;
                lm[rr][k*8 + w*2 + 1] = (unsigned)(m >> 32);
            }
        }
    }
    __syncthreads();
    {   // degree
        int rr = t >> 4, seg = t & 15, cnt = 0;
        #pragma unroll
        for (int k = 0; k < 16; ++k) cnt += __popc(lm[rr][seg*16 + k]);
        red[t] = cnt; __syncthreads();
        if (t < 16){
            int s = 0;
            #pragma unroll
            for (int k = 0; k < 16; ++k) s += red[t*16 + k];
            deg[grp*16 + t] = (float)s;
            invdeg[grp*16 + t] = 1.f / fmaxf((float)s, 1.f);
        }
    }
    // mP region for this group: contiguous 16 KiB; word W = g*16 + n = lm[n][g]
    unsigned* out = mP + (size_t)grp * 4096;
    #pragma unroll
    for (int s = 0; s < 16; ++s){
        int W = s*256 + t;
        out[W] = lm[W & 15][W >> 4];
    }
}

// ---------------------------------------------------------------------------
// setup: h0 gather (f32 hA + packed-bf16 hP), Wc = Wih@msgW, bc = Wih@msg_b+bih.
// hP layout: hP[((g*2+ch)*64 + quad*16 + n)*8 + j] = h[g*32+quad*8+j][ch*16+n]
// ---------------------------------------------------------------------------
__global__ __launch_bounds__(256) void k_setup(
    const int* __restrict__ af, const float* __restrict__ atom_emb,
    const float* __restrict__ msgW, const float* __restrict__ msgb,
    const float* __restrict__ Wih, const float* __restrict__ bih,
    float* __restrict__ hA, unsigned short* __restrict__ hP,
    float* __restrict__ Wc, float* __restrict__ bc)
{
    const int blk = blockIdx.x, t = threadIdx.x;
    if (blk < 1024){                       // h0: 8192*32
        int idx = blk*256 + t;
        int i = idx >> 5, e = idx & 31;
        float v = atom_emb[af[i]*EMBED + e];
        hA[idx] = v;
        int g = i >> 5, qd = (i >> 3) & 3, j8 = i & 7;
        hP[(size_t)((g*2 + (e>>4))*64 + qd*16 + (e&15))*8 + j8] = f2bf(v);
    } else if (blk < 1264){                // Wc: 10*96*64, K=256
        int o = (blk-1024)*256 + t;
        int d = o / 6144, r = o % 6144, g = r >> 6, e = r & 63;
        const float* wi = Wih  + (size_t)(d*96 + g)*256;
        const float* mw = msgW + (size_t)d*256*64 + e;
        float acc = 0.f;
        for (int hh = 0; hh < 256; ++hh) acc += wi[hh] * mw[hh*64];
        Wc[o] = acc;
    } else {                               // bc: 10*96
        int o = (blk-1264)*256 + t;
        if (o < 960){
            int d = o / 96;
            const float* wi = Wih + (size_t)o*256;   // o = d*96+g
            const float* mb = msgb + d*256;
            float acc = 0.f;
            for (int hh = 0; hh < 256; ++hh) acc += wi[hh] * mb[hh];
            bc[o] = acc + bih[o];
        }
    }
}

// ---------------------------------------------------------------------------
// per depth: neighbor sums via MFMA, NO LDS, NO barriers. grid = 512
// (8 K-eighths x 64 row-blocks of 128). Wave = 2 row-tiles (M=32) x 32 cols.
// B-frags = coalesced uint4 loads from packed hP; A-words = 64-B broadcast
// loads from packed mP; bit->bf16{0,1} expansion in registers.
// mfma_f32_16x16x32_bf16 (verified): A[m=lane&15][k=quad*8+j],
// B[k=quad*8+j][n=lane&15], D[quad*4+r][lane&15].
// ---------------------------------------------------------------------------
__global__ __launch_bounds__(256) void k_nei(const unsigned short* __restrict__ hP,
                                             const unsigned* __restrict__ mP,
                                             float* __restrict__ neipart)
{
    const int rb = blockIdx.x & 63;     // row block (128 rows)
    const int q  = blockIdx.x >> 6;     // K eighth (1024 cols)
    const int t = threadIdx.x, w = t >> 6, lane = t & 63;
    const int n = lane & 15, quad = lane >> 4;
    const int rt0 = rb*8 + w*2;         // first of this wave's 2 row-tiles

    f32x4 a00 = {0.f,0.f,0.f,0.f};      // tile0 x cols n
    f32x4 a01 = {0.f,0.f,0.f,0.f};      // tile0 x cols 16+n
    f32x4 a10 = {0.f,0.f,0.f,0.f};      // tile1 x cols n
    f32x4 a11 = {0.f,0.f,0.f,0.f};      // tile1 x cols 16+n

    const unsigned* m0 = mP + (size_t)rt0*4096 + n;
    const unsigned* m1 = m0 + 4096;
    #pragma unroll 4
    for (int kk = 0; kk < 32; ++kk){
        const int g = q*32 + kk;
        union { uint4 u; bf16x8 v; } b0, b1;
        b0.u = *(const uint4*)&hP[(size_t)((g*2+0)*64 + lane)*8];
        b1.u = *(const uint4*)&hP[(size_t)((g*2+1)*64 + lane)*8];
        unsigned by0 = (m0[g*16] >> (quad*8)) & 0xFFu;
        unsigned by1 = (m1[g*16] >> (quad*8)) & 0xFFu;
        union { unsigned u[4]; bf16x8 v; } af0, af1;
        af0.u[0] = ((by0 & 1u)  ? 0x3F80u : 0u) | ((by0 & 2u)   ? 0x3F800000u : 0u);
        af0.u[1] = ((by0 & 4u)  ? 0x3F80u : 0u) | ((by0 & 8u)   ? 0x3F800000u : 0u);
        af0.u[2] = ((by0 & 16u) ? 0x3F80u : 0u) | ((by0 & 32u)  ? 0x3F800000u : 0u);
        af0.u[3] = ((by0 & 64u) ? 0x3F80u : 0u) | ((by0 & 128u) ? 0x3F800000u : 0u);
        af1.u[0] = ((by1 & 1u)  ? 0x3F80u : 0u) | ((by1 & 2u)   ? 0x3F800000u : 0u);
        af1.u[1] = ((by1 & 4u)  ? 0x3F80u : 0u) | ((by1 & 8u)   ? 0x3F800000u : 0u);
        af1.u[2] = ((by1 & 16u) ? 0x3F80u : 0u) | ((by1 & 32u)  ? 0x3F800000u : 0u);
        af1.u[3] = ((by1 & 64u) ? 0x3F80u : 0u) | ((by1 & 128u) ? 0x3F800000u : 0u);
        a00 = __builtin_amdgcn_mfma_f32_16x16x32_bf16(af0.v, b0.v, a00, 0, 0, 0);
        a01 = __builtin_amdgcn_mfma_f32_16x16x32_bf16(af0.v, b1.v, a01, 0, 0, 0);
        a10 = __builtin_amdgcn_mfma_f32_16x16x32_bf16(af1.v, b0.v, a10, 0, 0, 0);
        a11 = __builtin_amdgcn_mfma_f32_16x16x32_bf16(af1.v, b1.v, a11, 0, 0, 0);
    }
    float* outp = neipart + (size_t)q * N_ATOMS * EMBED;
    #pragma unroll
    for (int r = 0; r < 4; ++r){
        int row0 = rt0*16 + quad*4 + r;
        int row1 = row0 + 16;
        outp[(size_t)row0*EMBED + n]      = a00[r];
        outp[(size_t)row0*EMBED + 16 + n] = a01[r];
        outp[(size_t)row1*EMBED + n]      = a10[r];
        outp[(size_t)row1*EMBED + 16 + n] = a11[r];
    }
}

// ---------------------------------------------------------------------------
// per depth: fused message+GRU. 256 blocks x 256 thr (full GPU). Block = 32
// atoms; thread (a32 = t&31, grp = t>>5) computes gates j = grp*4..grp*4+3.
// Writes f32 hout (+ out0 on last) and packed-bf16 hP for next depth.
// ---------------------------------------------------------------------------
__global__ __launch_bounds__(256) void k_gru(
    const float* __restrict__ hin, float* __restrict__ hout,
    const float* __restrict__ neipart,
    const float* __restrict__ invdeg, const float* __restrict__ deg,
    const float* __restrict__ Wc, const float* __restrict__ bc,
    const float* __restrict__ bihf, const float* __restrict__ bhhf,
    const float* __restrict__ Whhf,
    unsigned short* __restrict__ hP, float* __restrict__ out0, int last)
{
    __shared__ float xs[32][68];
    const int t = threadIdx.x, blk = blockIdx.x;
    {   // coalesced stage: h (1024 f) + nei sum over 8 eighths
        float4 v = *(const float4*)&hin[(size_t)blk*1024 + t*4];
        int a = t >> 3, e = (t*4) & 31;
        *(float4*)&xs[a][e] = v;
        float4 s = {0.f,0.f,0.f,0.f};
        #pragma unroll
        for (int q = 0; q < 8; ++q){
            float4 v2 = *(const float4*)&neipart[(size_t)q*N_ATOMS*EMBED + blk*1024 + t*4];
            s.x += v2.x; s.y += v2.y; s.z += v2.z; s.w += v2.w;
        }
        *(float4*)&xs[a][32 + e] = s;
    }
    __syncthreads();

    const int a32 = t & 31, grp = t >> 5;
    const int atom = blk*32 + a32;
    const float idg = invdeg[atom];
    const bool nz = deg[atom] > 0.f;
    float x[64];
    #pragma unroll
    for (int r = 0; r < 16; ++r){
        float4 v = *(const float4*)&xs[a32][r*4];
        x[r*4+0]=v.x; x[r*4+1]=v.y; x[r*4+2]=v.z; x[r*4+3]=v.w;
    }
    #pragma unroll
    for (int e = 32; e < 64; ++e) x[e] *= idg;

    const int g = atom >> 5, qd = (atom >> 3) & 3, j8 = atom & 7;
    #pragma unroll
    for (int jj = 0; jj < 4; ++jj){
        const int j = grp*4 + jj;
        const float* wr = Wc + j*64;
        const float* wz = Wc + (32+j)*64;
        const float* wn = Wc + (64+j)*64;
        float gr=0.f, gz=0.f, gn=0.f;
        #pragma unroll
        for (int e = 0; e < 64; ++e){ gr += wr[e]*x[e]; gz += wz[e]*x[e]; gn += wn[e]*x[e]; }
        if (nz){ gr += bc[j]; gz += bc[32+j]; gn += bc[64+j]; }
        else   { gr  = bihf[j]; gz = bihf[32+j]; gn = bihf[64+j]; }
        const float* vr = Whhf + j*32;
        const float* vz = Whhf + (32+j)*32;
        const float* vn = Whhf + (64+j)*32;
        float hr=bhhf[j], hz=bhhf[32+j], hn=bhhf[64+j];
        #pragma unroll
        for (int e = 0; e < 32; ++e){ hr += vr[e]*x[e]; hz += vz[e]*x[e]; hn += vn[e]*x[e]; }
        float rg = 1.f/(1.f + expf(-(gr+hr)));
        float zg = 1.f/(1.f + expf(-(gz+hz)));
        float ng = tanhf(gn + rg*hn);
        float hnew = (1.f - zg)*ng + zg*x[j];
        hout[(size_t)atom*EMBED + j] = hnew;
        hP[(size_t)((g*2 + (j>>4))*64 + qd*16 + (j&15))*8 + j8] = f2bf(hnew);
        if (last) out0[(size_t)atom*EMBED + j] = hnew;
    }
}

// ---------------------------------------------------------------------------
__global__ __launch_bounds__(256) void k_bond(const int* __restrict__ bfeat,
                                              const float* __restrict__ bondf,
                                              float* __restrict__ out1)
{
    int idx = blockIdx.x*256 + threadIdx.x;
    out1[idx] = bondf[bfeat[idx >> 5]*EMBED + (idx & 31)];
}

// ---------------------------------------------------------------------------
__global__ __launch_bounds__(256) void k_pool(
    const float* __restrict__ h, const int* __restrict__ batch,
    const float* __restrict__ poolW, const float* __restrict__ poolb,
    float* __restrict__ out2)
{
    const int b = blockIdx.x, t = threadIdx.x;
    int lo, hi;
    { int l = 0, r = N_ATOMS; while (l < r){ int m = (l+r)>>1; if (batch[m] < b)   l = m+1; else r = m; } lo = l; }
    { int l = 0, r = N_ATOMS; while (l < r){ int m = (l+r)>>1; if (batch[m] < b+1) l = m+1; else r = m; } hi = l; }
    const int cnt = hi - lo;
    __shared__ float ps[8][32];
    __shared__ float mean[32];
    const int e = t & 31, g = t >> 5;
    float acc = 0.f;
    for (int a = lo + g; a < hi; a += 8) acc += h[(size_t)a*EMBED + e];
    ps[g][e] = acc; __syncthreads();
    if (t < 32){
        float s = 0.f;
        #pragma unroll
        for (int gg = 0; gg < 8; ++gg) s += ps[gg][t];
        mean[t] = (cnt > 0) ? s / (float)cnt : 0.f;
    }
    __syncthreads();
    float emb = poolb[t];
    #pragma unroll
    for (int ee = 0; ee < 32; ++ee) emb += mean[ee] * poolW[t*32 + ee];
    out2[b*256 + t] = emb;
}

// ---------------------------------------------------------------------------
extern "C" void kernel_launch(void* const* d_in, const int* in_sizes, int n_in,
                              void* d_out, int out_size, void* d_ws, size_t ws_size,
                              hipStream_t stream)
{
    (void)in_sizes; (void)n_in; (void)out_size;
    const int* af   = (const int*)d_in[0];
    const int* bfe  = (const int*)d_in[1];
    const int* A    = (const int*)d_in[2];
    const int* bidx = (const int*)d_in[3];
    const float* atom_emb = (const float*)d_in[4];
    const float* bond_emb = (const float*)d_in[5];
    const float* msgW  = (const float*)d_in[6];
    const float* msgb  = (const float*)d_in[7];
    const float* Wih   = (const float*)d_in[8];
    const float* Whh   = (const float*)d_in[9];
    const float* bih   = (const float*)d_in[10];
    const float* bhh   = (const float*)d_in[11];
    const float* poolW = (const float*)d_in[12];
    const float* poolb = (const float*)d_in[13];

    // outputs are FLOAT32: h [8192*32] | bond [16384*32] | graph [256*256]
    float* out0 = (float*)d_out;
    float* out1 = out0 + 262144;
    float* out2 = out1 + 524288;

    // deg/invdeg live in the out2 region (overwritten by k_pool at the end);
    // proven-safe pattern, avoids racing preA's A-row reads in both paths.
    float* deg    = out2;            // 8192 f
    float* invdeg = out2 + 8192;     // 8192 f

    unsigned*       mP;
    float*          hA; float* hB; float* Wc; float* bc; float* neipart;
    unsigned short* hP;
    const int wsok = (ws_size >= (size_t)33554432) ? 1 : 0;
    if (wsok){
        char* W = (char*)d_ws;
        mP      = (unsigned*)(W + 0);                 // 8 MiB
        hP      = (unsigned short*)(W + 8388608);     // 512 KiB
        hA      = (float*)(W + 9437184);              // 1 MiB
        hB      = (float*)(W + 10485760);             // 1 MiB
        Wc      = (float*)(W + 11534336);             // 240 KiB
        bc      = (float*)(W + 11796480);
        neipart = (float*)(W + 12582912);             // 8 MiB
        k_preA<<<dim3(512), dim3(256), 0, stream>>>(A, mP, deg, invdeg, 0);
    } else {
        // A-buffer scratch. mP at the tail (overlays rows 7936..8191's data);
        // k_preA stages all reads before writing, and chunk order guarantees
        // every overlaid row is already consumed:
        //   chunk1 {grp 511} (self-overlay, staged), chunk2 {496..510}
        //   (overlay rows 8184..8191), chunk3 {0..495} (overlay 7936..8183).
        char* Ab = (char*)d_in[2];
        hA      = (float*)(Ab + 0);
        hB      = (float*)(Ab + 1048576);
        hP      = (unsigned short*)(Ab + 2097152);
        Wc      = (float*)(Ab + 2621440);
        bc      = (float*)(Ab + 2867200);
        neipart = (float*)(Ab + 4194304);             // 8 MiB
        mP      = (unsigned*)(Ab + 260046848);        // last 8 MiB
        k_preA<<<dim3(1),   dim3(256), 0, stream>>>(A, mP, deg, invdeg, 511);
        k_preA<<<dim3(15),  dim3(256), 0, stream>>>(A, mP, deg, invdeg, 496);
        k_preA<<<dim3(496), dim3(256), 0, stream>>>(A, mP, deg, invdeg, 0);
    }
    k_setup<<<dim3(1268), dim3(256), 0, stream>>>(af, atom_emb, msgW, msgb,
        Wih, bih, hA, hP, Wc, bc);

    float* hin = hA; float* hout = hB;
    for (int d = 0; d < DEPTHN; ++d){
        k_nei<<<dim3(512), dim3(256), 0, stream>>>(hP, mP, neipart);
        k_gru<<<dim3(256), dim3(256), 0, stream>>>(hin, hout, neipart, invdeg, deg,
            Wc + d*6144, bc + d*96, bih + d*96, bhh + d*96, Whh + d*3072,
            hP, out0, (d == DEPTHN-1) ? 1 : 0);
        float* tmp = hin; hin = hout; hout = tmp;
    }
    k_bond<<<dim3(2048), dim3(256), 0, stream>>>(bfe, bond_emb, out1);
    k_pool<<<dim3(256), dim3(256), 0, stream>>>(hin, bidx, poolW, poolb, out2);
}

// Round 12
// 761.769 us; speedup vs baseline: 1.2307x; 1.2307x over previous
//
#include <hip/hip_runtime.h>
#include <stdint.h>

#define N_ATOMS 8192
#define EMBED   32
#define DEPTHN  10

typedef short bf16x8 __attribute__((ext_vector_type(8)));
typedef float f32x4  __attribute__((ext_vector_type(4)));

__device__ __forceinline__ unsigned short f2bf(float f){
    unsigned u = __builtin_bit_cast(unsigned, f);
    u = u + 0x7FFFu + ((u >> 16) & 1u);
    return (unsigned short)(u >> 16);
}

// ---------------------------------------------------------------------------
// k_preA (R10-proven ~43us form): one row per block, 8192 blocks. Row-major
// mask64 writes, LDS staged (all reads of the row complete before any global
// write -> safe under A-tail aliasing fallback). u32 word g of row i covers
// columns 32g..32g+31.
// ---------------------------------------------------------------------------
__global__ __launch_bounds__(256) void k_preA(const int* __restrict__ A,
                                              unsigned long long* __restrict__ mask,
                                              int row0)
{
    const int i = row0 + blockIdx.x;
    const int t = threadIdx.x, w = t >> 6, l = t & 63;
    const int* row = A + (size_t)i * N_ATOMS;
    __shared__ unsigned long long lm[128];
    #pragma unroll
    for (int k = 0; k < 32; ++k){
        int j = k*256 + t;
        unsigned long long m = __ballot(row[j] != 0);
        if (l == 0) lm[k*4 + w] = m;
    }
    __syncthreads();
    if (t < 128) mask[(size_t)i*128 + t] = lm[t];
}

// ---------------------------------------------------------------------------
// k_pack: transpose row-major mask -> packed MFMA-A-fragment order mP
//   mP[grp*4096 + g*16 + n] = rowMajor[(grp*16+n)*256 + g]
// plus deg/invdeg. 512 blocks (one per 16-row group), 16 KiB via LDS,
// coalesced reads AND writes; 260-stride pad -> only 2-way LDS conflicts.
// ---------------------------------------------------------------------------
__global__ __launch_bounds__(256) void k_pack(const unsigned* __restrict__ maskRM,
                                              unsigned* __restrict__ mP,
                                              float* __restrict__ deg,
                                              float* __restrict__ invdeg)
{
    const int grp = blockIdx.x, t = threadIdx.x;
    __shared__ unsigned lm[16*260];
    __shared__ int red[256];
    #pragma unroll
    for (int s = 0; s < 16; ++s)
        lm[s*260 + t] = maskRM[(size_t)grp*4096 + s*256 + t];
    __syncthreads();
    {   // degree: thread t -> row t>>4, segment t&15 (16 words each)
        int r = t >> 4, seg = t & 15, cnt = 0;
        #pragma unroll
        for (int k = 0; k < 16; ++k) cnt += __popc(lm[r*260 + seg*16 + k]);
        red[t] = cnt; __syncthreads();
        if (t < 16){
            int s = 0;
            #pragma unroll
            for (int k = 0; k < 16; ++k) s += red[t*16 + k];
            deg[grp*16 + t] = (float)s;
            invdeg[grp*16 + t] = 1.f / fmaxf((float)s, 1.f);
        }
    }
    unsigned* out = mP + (size_t)grp*4096;
    #pragma unroll
    for (int s = 0; s < 16; ++s){
        int W = s*256 + t;
        out[W] = lm[(W & 15)*260 + (W >> 4)];
    }
}

// ---------------------------------------------------------------------------
// setup: h0 gather (f32 hA + packed-bf16 hP), Wc = Wih@msgW, bc = Wih@msg_b+bih.
// hP layout: hP[((g*2+ch)*64 + quad*16 + n)*8 + j] = h[g*32+quad*8+j][ch*16+n]
// ---------------------------------------------------------------------------
__global__ __launch_bounds__(256) void k_setup(
    const int* __restrict__ af, const float* __restrict__ atom_emb,
    const float* __restrict__ msgW, const float* __restrict__ msgb,
    const float* __restrict__ Wih, const float* __restrict__ bih,
    float* __restrict__ hA, unsigned short* __restrict__ hP,
    float* __restrict__ Wc, float* __restrict__ bc)
{
    const int blk = blockIdx.x, t = threadIdx.x;
    if (blk < 1024){                       // h0: 8192*32
        int idx = blk*256 + t;
        int i = idx >> 5, e = idx & 31;
        float v = atom_emb[af[i]*EMBED + e];
        hA[idx] = v;
        int g = i >> 5, qd = (i >> 3) & 3, j8 = i & 7;
        hP[(size_t)((g*2 + (e>>4))*64 + qd*16 + (e&15))*8 + j8] = f2bf(v);
    } else if (blk < 1264){                // Wc: 10*96*64, K=256
        int o = (blk-1024)*256 + t;
        int d = o / 6144, r = o % 6144, g = r >> 6, e = r & 63;
        const float* wi = Wih  + (size_t)(d*96 + g)*256;
        const float* mw = msgW + (size_t)d*256*64 + e;
        float acc = 0.f;
        for (int hh = 0; hh < 256; ++hh) acc += wi[hh] * mw[hh*64];
        Wc[o] = acc;
    } else {                               // bc: 10*96
        int o = (blk-1264)*256 + t;
        if (o < 960){
            int d = o / 96;
            const float* wi = Wih + (size_t)o*256;   // o = d*96+g
            const float* mb = msgb + d*256;
            float acc = 0.f;
            for (int hh = 0; hh < 256; ++hh) acc += wi[hh] * mb[hh];
            bc[o] = acc + bih[o];
        }
    }
}

// ---------------------------------------------------------------------------
// per depth: neighbor sums via MFMA, NO LDS, NO barriers (R11-verified).
// grid = 512 (8 K-eighths x 64 row-blocks of 128). Wave = 2 row-tiles x 32.
// ---------------------------------------------------------------------------
__global__ __launch_bounds__(256) void k_nei(const unsigned short* __restrict__ hP,
                                             const unsigned* __restrict__ mP,
                                             float* __restrict__ neipart)
{
    const int rb = blockIdx.x & 63;     // row block (128 rows)
    const int q  = blockIdx.x >> 6;     // K eighth (1024 cols)
    const int t = threadIdx.x, w = t >> 6, lane = t & 63;
    const int n = lane & 15, quad = lane >> 4;
    const int rt0 = rb*8 + w*2;

    f32x4 a00 = {0.f,0.f,0.f,0.f};
    f32x4 a01 = {0.f,0.f,0.f,0.f};
    f32x4 a10 = {0.f,0.f,0.f,0.f};
    f32x4 a11 = {0.f,0.f,0.f,0.f};

    const unsigned* m0 = mP + (size_t)rt0*4096 + n;
    const unsigned* m1 = m0 + 4096;
    #pragma unroll 4
    for (int kk = 0; kk < 32; ++kk){
        const int g = q*32 + kk;
        union { uint4 u; bf16x8 v; } b0, b1;
        b0.u = *(const uint4*)&hP[(size_t)((g*2+0)*64 + lane)*8];
        b1.u = *(const uint4*)&hP[(size_t)((g*2+1)*64 + lane)*8];
        unsigned by0 = (m0[g*16] >> (quad*8)) & 0xFFu;
        unsigned by1 = (m1[g*16] >> (quad*8)) & 0xFFu;
        union { unsigned u[4]; bf16x8 v; } af0, af1;
        af0.u[0] = ((by0 & 1u)  ? 0x3F80u : 0u) | ((by0 & 2u)   ? 0x3F800000u : 0u);
        af0.u[1] = ((by0 & 4u)  ? 0x3F80u : 0u) | ((by0 & 8u)   ? 0x3F800000u : 0u);
        af0.u[2] = ((by0 & 16u) ? 0x3F80u : 0u) | ((by0 & 32u)  ? 0x3F800000u : 0u);
        af0.u[3] = ((by0 & 64u) ? 0x3F80u : 0u) | ((by0 & 128u) ? 0x3F800000u : 0u);
        af1.u[0] = ((by1 & 1u)  ? 0x3F80u : 0u) | ((by1 & 2u)   ? 0x3F800000u : 0u);
        af1.u[1] = ((by1 & 4u)  ? 0x3F80u : 0u) | ((by1 & 8u)   ? 0x3F800000u : 0u);
        af1.u[2] = ((by1 & 16u) ? 0x3F80u : 0u) | ((by1 & 32u)  ? 0x3F800000u : 0u);
        af1.u[3] = ((by1 & 64u) ? 0x3F80u : 0u) | ((by1 & 128u) ? 0x3F800000u : 0u);
        a00 = __builtin_amdgcn_mfma_f32_16x16x32_bf16(af0.v, b0.v, a00, 0, 0, 0);
        a01 = __builtin_amdgcn_mfma_f32_16x16x32_bf16(af0.v, b1.v, a01, 0, 0, 0);
        a10 = __builtin_amdgcn_mfma_f32_16x16x32_bf16(af1.v, b0.v, a10, 0, 0, 0);
        a11 = __builtin_amdgcn_mfma_f32_16x16x32_bf16(af1.v, b1.v, a11, 0, 0, 0);
    }
    float* outp = neipart + (size_t)q * N_ATOMS * EMBED;
    #pragma unroll
    for (int r = 0; r < 4; ++r){
        int row0 = rt0*16 + quad*4 + r;
        int row1 = row0 + 16;
        outp[(size_t)row0*EMBED + n]      = a00[r];
        outp[(size_t)row0*EMBED + 16 + n] = a01[r];
        outp[(size_t)row1*EMBED + n]      = a10[r];
        outp[(size_t)row1*EMBED + 16 + n] = a11[r];
    }
}

// ---------------------------------------------------------------------------
// per depth: fused message+GRU (R11-verified). 256 blocks x 256 thr.
// ---------------------------------------------------------------------------
__global__ __launch_bounds__(256) void k_gru(
    const float* __restrict__ hin, float* __restrict__ hout,
    const float* __restrict__ neipart,
    const float* __restrict__ invdeg, const float* __restrict__ deg,
    const float* __restrict__ Wc, const float* __restrict__ bc,
    const float* __restrict__ bihf, const float* __restrict__ bhhf,
    const float* __restrict__ Whhf,
    unsigned short* __restrict__ hP, float* __restrict__ out0, int last)
{
    __shared__ float xs[32][68];
    const int t = threadIdx.x, blk = blockIdx.x;
    {
        float4 v = *(const float4*)&hin[(size_t)blk*1024 + t*4];
        int a = t >> 3, e = (t*4) & 31;
        *(float4*)&xs[a][e] = v;
        float4 s = {0.f,0.f,0.f,0.f};
        #pragma unroll
        for (int q = 0; q < 8; ++q){
            float4 v2 = *(const float4*)&neipart[(size_t)q*N_ATOMS*EMBED + blk*1024 + t*4];
            s.x += v2.x; s.y += v2.y; s.z += v2.z; s.w += v2.w;
        }
        *(float4*)&xs[a][32 + e] = s;
    }
    __syncthreads();

    const int a32 = t & 31, grp = t >> 5;
    const int atom = blk*32 + a32;
    const float idg = invdeg[atom];
    const bool nz = deg[atom] > 0.f;
    float x[64];
    #pragma unroll
    for (int r = 0; r < 16; ++r){
        float4 v = *(const float4*)&xs[a32][r*4];
        x[r*4+0]=v.x; x[r*4+1]=v.y; x[r*4+2]=v.z; x[r*4+3]=v.w;
    }
    #pragma unroll
    for (int e = 32; e < 64; ++e) x[e] *= idg;

    const int g = atom >> 5, qd = (atom >> 3) & 3, j8 = atom & 7;
    #pragma unroll
    for (int jj = 0; jj < 4; ++jj){
        const int j = grp*4 + jj;
        const float* wr = Wc + j*64;
        const float* wz = Wc + (32+j)*64;
        const float* wn = Wc + (64+j)*64;
        float gr=0.f, gz=0.f, gn=0.f;
        #pragma unroll
        for (int e = 0; e < 64; ++e){ gr += wr[e]*x[e]; gz += wz[e]*x[e]; gn += wn[e]*x[e]; }
        if (nz){ gr += bc[j]; gz += bc[32+j]; gn += bc[64+j]; }
        else   { gr  = bihf[j]; gz = bihf[32+j]; gn = bihf[64+j]; }
        const float* vr = Whhf + j*32;
        const float* vz = Whhf + (32+j)*32;
        const float* vn = Whhf + (64+j)*32;
        float hr=bhhf[j], hz=bhhf[32+j], hn=bhhf[64+j];
        #pragma unroll
        for (int e = 0; e < 32; ++e){ hr += vr[e]*x[e]; hz += vz[e]*x[e]; hn += vn[e]*x[e]; }
        float rg = 1.f/(1.f + expf(-(gr+hr)));
        float zg = 1.f/(1.f + expf(-(gz+hz)));
        float ng = tanhf(gn + rg*hn);
        float hnew = (1.f - zg)*ng + zg*x[j];
        hout[(size_t)atom*EMBED + j] = hnew;
        hP[(size_t)((g*2 + (j>>4))*64 + qd*16 + (j&15))*8 + j8] = f2bf(hnew);
        if (last) out0[(size_t)atom*EMBED + j] = hnew;
    }
}

// ---------------------------------------------------------------------------
__global__ __launch_bounds__(256) void k_bond(const int* __restrict__ bfeat,
                                              const float* __restrict__ bondf,
                                              float* __restrict__ out1)
{
    int idx = blockIdx.x*256 + threadIdx.x;
    out1[idx] = bondf[bfeat[idx >> 5]*EMBED + (idx & 31)];
}

// ---------------------------------------------------------------------------
__global__ __launch_bounds__(256) void k_pool(
    const float* __restrict__ h, const int* __restrict__ batch,
    const float* __restrict__ poolW, const float* __restrict__ poolb,
    float* __restrict__ out2)
{
    const int b = blockIdx.x, t = threadIdx.x;
    int lo, hi;
    { int l = 0, r = N_ATOMS; while (l < r){ int m = (l+r)>>1; if (batch[m] < b)   l = m+1; else r = m; } lo = l; }
    { int l = 0, r = N_ATOMS; while (l < r){ int m = (l+r)>>1; if (batch[m] < b+1) l = m+1; else r = m; } hi = l; }
    const int cnt = hi - lo;
    __shared__ float ps[8][32];
    __shared__ float mean[32];
    const int e = t & 31, g = t >> 5;
    float acc = 0.f;
    for (int a = lo + g; a < hi; a += 8) acc += h[(size_t)a*EMBED + e];
    ps[g][e] = acc; __syncthreads();
    if (t < 32){
        float s = 0.f;
        #pragma unroll
        for (int gg = 0; gg < 8; ++gg) s += ps[gg][t];
        mean[t] = (cnt > 0) ? s / (float)cnt : 0.f;
    }
    __syncthreads();
    float emb = poolb[t];
    #pragma unroll
    for (int ee = 0; ee < 32; ++ee) emb += mean[ee] * poolW[t*32 + ee];
    out2[b*256 + t] = emb;
}

// ---------------------------------------------------------------------------
extern "C" void kernel_launch(void* const* d_in, const int* in_sizes, int n_in,
                              void* d_out, int out_size, void* d_ws, size_t ws_size,
                              hipStream_t stream)
{
    (void)in_sizes; (void)n_in; (void)out_size;
    const int* af   = (const int*)d_in[0];
    const int* bfe  = (const int*)d_in[1];
    const int* A    = (const int*)d_in[2];
    const int* bidx = (const int*)d_in[3];
    const float* atom_emb = (const float*)d_in[4];
    const float* bond_emb = (const float*)d_in[5];
    const float* msgW  = (const float*)d_in[6];
    const float* msgb  = (const float*)d_in[7];
    const float* Wih   = (const float*)d_in[8];
    const float* Whh   = (const float*)d_in[9];
    const float* bih   = (const float*)d_in[10];
    const float* bhh   = (const float*)d_in[11];
    const float* poolW = (const float*)d_in[12];
    const float* poolb = (const float*)d_in[13];

    // outputs are FLOAT32: h [8192*32] | bond [16384*32] | graph [256*256]
    float* out0 = (float*)d_out;
    float* out1 = out0 + 262144;
    float* out2 = out1 + 524288;

    // deg/invdeg in out2 region (k_pool overwrites last) — proven pattern
    float* deg    = out2;
    float* invdeg = out2 + 8192;

    unsigned long long* maskRM;
    unsigned*       mP;
    float*          hA; float* hB; float* Wc; float* bc; float* neipart;
    unsigned short* hP;
    const int wsok = (ws_size >= (size_t)33554432) ? 1 : 0;
    if (wsok){
        char* W = (char*)d_ws;
        maskRM  = (unsigned long long*)(W + 0);       // 8 MiB row-major
        mP      = (unsigned*)(W + 8388608);           // 8 MiB packed
        hP      = (unsigned short*)(W + 16777216);    // 512 KiB
        hA      = (float*)(W + 17825792);             // 1 MiB
        hB      = (float*)(W + 18874368);             // 1 MiB
        Wc      = (float*)(W + 19922944);             // 240 KiB
        bc      = (float*)(W + 20185088);
        neipart = (float*)(W + 20971520);             // 8 MiB
        k_preA<<<dim3(8192), dim3(256), 0, stream>>>(A, maskRM, 0);
    } else {
        // A-buffer scratch, R10-proven: row-major mask at the A tail
        // (overlays rows 7936..8191), descending phases + LDS staging.
        char* Ab = (char*)d_in[2];
        hA      = (float*)(Ab + 0);
        hB      = (float*)(Ab + 1048576);
        hP      = (unsigned short*)(Ab + 2097152);
        Wc      = (float*)(Ab + 2621440);
        bc      = (float*)(Ab + 2867200);
        neipart = (float*)(Ab + 4194304);             // 8 MiB, ends 12.5 MiB
        mP      = (unsigned*)(Ab + 13631488);         // 8 MiB, ends 21.6 MiB
        maskRM  = (unsigned long long*)(Ab + 260046848);
        k_preA<<<dim3(1),    dim3(256), 0, stream>>>(A, maskRM, 8191);
        k_preA<<<dim3(7),    dim3(256), 0, stream>>>(A, maskRM, 8184);
        k_preA<<<dim3(248),  dim3(256), 0, stream>>>(A, maskRM, 7936);
        k_preA<<<dim3(7936), dim3(256), 0, stream>>>(A, maskRM, 0);
    }
    k_pack<<<dim3(512), dim3(256), 0, stream>>>((const unsigned*)maskRM, mP,
        deg, invdeg);
    k_setup<<<dim3(1268), dim3(256), 0, stream>>>(af, atom_emb, msgW, msgb,
        Wih, bih, hA, hP, Wc, bc);

    float* hin = hA; float* hout = hB;
    for (int d = 0; d < DEPTHN; ++d){
        k_nei<<<dim3(512), dim3(256), 0, stream>>>(hP, mP, neipart);
        k_gru<<<dim3(256), dim3(256), 0, stream>>>(hin, hout, neipart, invdeg, deg,
            Wc + d*6144, bc + d*96, bih + d*96, bhh + d*96, Whh + d*3072,
            hP, out0, (d == DEPTHN-1) ? 1 : 0);
        float* tmp = hin; hin = hout; hout = tmp;
    }
    k_bond<<<dim3(2048), dim3(256), 0, stream>>>(bfe, bond_emb, out1);
    k_pool<<<dim3(256), dim3(256), 0, stream>>>(hin, bidx, poolW, poolb, out2);
}